// Round 5
// baseline (1119.515 us; speedup 1.0000x reference)
//
#include <hip/hip_runtime.h>
#include <hip/hip_cooperative_groups.h>
#include <math.h>

namespace cg = cooperative_groups;

// ---------------------------------------------------------------------------
// VariationalGATEncoder round 5: ONE cooperative mega-kernel.
// R2 vs R4 accounting showed ~10us per-dispatch overhead x 17 dispatches
// dominates (~180us of 430). All phases fused into one kernel with
// grid.sync() barriers:
//  P0 transpose W + zero counters/scores
//  P1 count_edges   P2 chunk scan   P3 chunk-prefix add   P4 scatter + GEMM1
//  (GEMM epilogue computes attention scores via f32 atomicAdd - arrays
//   zeroed in P0; R3's fusion loss was the alpha kernels, not this)
//  P5 m,z per node  P6 weighted gather -> h   P7 GEMM2(+scores)
//  P8 m,z           P9 dual-head gather -> out
// p = exp(e-m)*zinv computed inline in gathers (s arrays are L2-resident),
// so no per-edge p arrays are materialized.
// ---------------------------------------------------------------------------

#define NN 50000
#define NCHUNK 196   // ceil(50000/256)

typedef __attribute__((ext_vector_type(8))) short bf16x8;
typedef __attribute__((ext_vector_type(4))) float f32x4;

__device__ __forceinline__ float bf2f(unsigned short u) {
    return __uint_as_float(((unsigned int)u) << 16);
}
__device__ __forceinline__ unsigned short f2bf(float f) {
    unsigned int i = __float_as_uint(f);
    unsigned int r = i + 0x7fffu + ((i >> 16) & 1u);   // RNE
    return (unsigned short)(r >> 16);
}
__device__ __forceinline__ void cvt2(unsigned int d, float& lo, float& hi) {
    lo = __uint_as_float(d << 16);
    hi = __uint_as_float(d & 0xffff0000u);
}
__device__ __forceinline__ void fma8(float* acc, uint4 d, float w) {
    float f0, f1, f2, f3, f4, f5, f6, f7;
    cvt2(d.x, f0, f1); cvt2(d.y, f2, f3); cvt2(d.z, f4, f5); cvt2(d.w, f6, f7);
    acc[0] += w * f0; acc[1] += w * f1; acc[2] += w * f2; acc[3] += w * f3;
    acc[4] += w * f4; acc[5] += w * f5; acc[6] += w * f6; acc[7] += w * f7;
}

struct GatP {
    const float* x;
    const int* src;
    const int* dst;
    int E;
    const float *W1, *a_src1, *a_dst1, *b1;
    const float *Wmu, *aSmu, *aDmu, *bmu;
    const float *Wls, *aSls, *aDls, *bls;
    unsigned short *W1t, *Wct, *hlin, *h, *hcat;
    float *s1s, *s1d, *sms, *smd, *slsv, *sld;   // 6 contiguous score arrays
    float *m1, *zi1, *mmu, *zimu, *mls, *zils;
    int *cnt, *cursor, *bsum, *row_start, *sperm;
    float *out_mu, *out_ls;
};

// 128x128x256 MFMA GEMM tile (unit = mtile*2 + nhalf) + fused score epilogue.
template <bool XF32>
__device__ __forceinline__ void gemm_unit(const GatP& P, int unit,
                                          unsigned short* As, unsigned short* Bs) {
    const int t = threadIdx.x;
    int lane = t & 63, w = t >> 6;
    int wm = w & 1, wn = w >> 1;
    int l15 = lane & 15, quad = lane >> 4;
    int mbase = (unit >> 1) * 128, nbase = (unit & 1) * 128;
    const unsigned short* Bt = XF32 ? P.W1t : P.Wct;
    unsigned short* C_ = XF32 ? P.hlin : P.hcat;

    f32x4 acc[4][4];
    const f32x4 zero = {0.f, 0.f, 0.f, 0.f};
#pragma unroll
    for (int mt = 0; mt < 4; mt++)
#pragma unroll
        for (int nt = 0; nt < 4; nt++) acc[mt][nt] = zero;

    for (int k0 = 0; k0 < 256; k0 += 32) {
#pragma unroll
        for (int i = t; i < 512; i += 256) {
            int row = i >> 2, seg = i & 3;
            int gr = mbase + row;
            if constexpr (XF32) {
                float4 a0 = make_float4(0.f, 0.f, 0.f, 0.f), a1 = a0;
                if (gr < NN) {
                    const float* ap = P.x + (size_t)gr * 256 + k0 + seg * 8;
                    a0 = *(const float4*)ap;
                    a1 = *(const float4*)(ap + 4);
                }
                ushort4 lo, hi;
                lo.x = f2bf(a0.x); lo.y = f2bf(a0.y); lo.z = f2bf(a0.z); lo.w = f2bf(a0.w);
                hi.x = f2bf(a1.x); hi.y = f2bf(a1.y); hi.z = f2bf(a1.z); hi.w = f2bf(a1.w);
                *(ushort4*)(&As[row * 40 + seg * 8]) = lo;
                *(ushort4*)(&As[row * 40 + seg * 8 + 4]) = hi;
            } else {
                float4 va = make_float4(0.f, 0.f, 0.f, 0.f);
                if (gr < NN) va = *(const float4*)(P.h + (size_t)gr * 256 + k0 + seg * 8);
                *(float4*)(&As[row * 40 + seg * 8]) = va;
            }
            float4 vb = *(const float4*)(Bt + (size_t)(nbase + row) * 256 + k0 + seg * 8);
            *(float4*)(&Bs[row * 40 + seg * 8]) = vb;
        }
        __syncthreads();
        bf16x8 af[4], bfr[4];
#pragma unroll
        for (int mt = 0; mt < 4; mt++)
            af[mt] = *(const bf16x8*)(&As[(wm * 64 + mt * 16 + l15) * 40 + quad * 8]);
#pragma unroll
        for (int nt = 0; nt < 4; nt++)
            bfr[nt] = *(const bf16x8*)(&Bs[(wn * 64 + nt * 16 + l15) * 40 + quad * 8]);
#pragma unroll
        for (int mt = 0; mt < 4; mt++)
#pragma unroll
            for (int nt = 0; nt < 4; nt++)
                acc[mt][nt] = __builtin_amdgcn_mfma_f32_16x16x32_bf16(af[mt], bfr[nt], acc[mt][nt], 0, 0, 0);
        __syncthreads();
    }

    // epilogue: C store + score partials
    const float *aS, *aD;
    float *sS, *sD;
    int aoff;
    if constexpr (XF32) {
        aS = P.a_src1; aD = P.a_dst1; sS = P.s1s; sD = P.s1d; aoff = nbase;
    } else {
        int nh = unit & 1;
        aS = nh ? P.aSls : P.aSmu;  aD = nh ? P.aDls : P.aDmu;
        sS = nh ? P.slsv : P.sms;   sD = nh ? P.sld  : P.smd;
        aoff = 0;
    }
    float as_[4], ad_[4];
#pragma unroll
    for (int nt = 0; nt < 4; nt++) {
        int ncol = aoff + wn * 64 + nt * 16 + l15;
        as_[nt] = aS[ncol];
        ad_[nt] = aD[ncol];
    }
#pragma unroll
    for (int mt = 0; mt < 4; mt++) {
#pragma unroll
        for (int r = 0; r < 4; r++) {
            int m_ = mbase + wm * 64 + mt * 16 + quad * 4 + r;
            bool ok = m_ < NN;
            float ps = 0.f, pd = 0.f;
#pragma unroll
            for (int nt = 0; nt < 4; nt++) {
                float val = acc[mt][nt][r];
                ps += val * as_[nt];
                pd += val * ad_[nt];
                if (ok) C_[(size_t)m_ * 256 + nbase + wn * 64 + nt * 16 + l15] = f2bf(val);
            }
#pragma unroll
            for (int off = 1; off < 16; off <<= 1) {
                ps += __shfl_xor(ps, off);
                pd += __shfl_xor(pd, off);
            }
            if (ok && l15 == 0) {
                atomicAdd(&sS[m_], ps);
                atomicAdd(&sD[m_], pd);
            }
        }
    }
}

__global__ __launch_bounds__(256, 2) void gat_mega(GatP P) {
    cg::grid_group grid = cg::this_grid();
    __shared__ __align__(16) unsigned short As[128 * 40];
    __shared__ __align__(16) unsigned short Bs[128 * 40];
    __shared__ int ilds[256];

    const int t = threadIdx.x, bid = blockIdx.x, nb = gridDim.x;
    const int gtid = bid * 256 + t, gsz = nb * 256;
    const int lane = t & 63, wid = t >> 6;
    const int half = lane >> 5, l31 = lane & 31;
    const int gw = bid * 4 + wid, nw = nb * 4;
    const int E = P.E;

    // ---- P0: transposes + zero counters and score arrays ----
    for (int i = gtid; i < 65536; i += gsz) {
        int n = i >> 8, k = i & 255;
        P.W1t[(size_t)n * 256 + k] = f2bf(P.W1[(size_t)k * 256 + n]);
    }
    for (int i = gtid; i < 65536; i += gsz) {
        int n = i >> 8, k = i & 255;
        float v = (n < 128) ? P.Wmu[(size_t)k * 128 + n] : P.Wls[(size_t)k * 128 + (n - 128)];
        P.Wct[(size_t)n * 256 + k] = f2bf(v);
    }
    for (int i = gtid; i < 2 * NN; i += gsz) P.cnt[i] = 0;          // cnt + cursor contiguous
    for (int i = gtid; i < 6 * NN; i += gsz) P.s1s[i] = 0.f;        // 6 score arrays contiguous
    grid.sync();

    // ---- P1: count ----
    for (int e = gtid; e < E; e += gsz) atomicAdd(&P.cnt[P.dst[e]], 1);
    grid.sync();

    // ---- P2: per-chunk (256) exclusive scan ----
    for (int c = bid; c < NCHUNK; c += nb) {
        int gi = c * 256 + t;
        int v = (gi < NN) ? P.cnt[gi] : 0;
        int x = v;
#pragma unroll
        for (int off = 1; off < 64; off <<= 1) {
            int u = __shfl_up(x, off);
            if (lane >= off) x += u;
        }
        if (lane == 63) ilds[wid] = x;
        __syncthreads();
        int woff = 0;
        for (int k2 = 0; k2 < wid; k2++) woff += ilds[k2];
        if (gi < NN) P.row_start[gi] = woff + x - v;
        if (t == 0) P.bsum[c] = ilds[0] + ilds[1] + ilds[2] + ilds[3];
        __syncthreads();
    }
    grid.sync();

    // ---- P3: add chunk prefixes (each block redundantly scans bsum) ----
    {
        int bv = (t < NCHUNK) ? P.bsum[t] : 0;
        ilds[t] = bv;
        __syncthreads();
        for (int off = 1; off < 256; off <<= 1) {
            int add = (t >= off) ? ilds[t - off] : 0;
            __syncthreads();
            ilds[t] += add;
            __syncthreads();
        }
        int excl = ilds[t] - bv;
        __syncthreads();
        ilds[t] = excl;
        __syncthreads();
        for (int gi = gtid; gi < NN; gi += gsz) P.row_start[gi] += ilds[gi >> 8];
        if (gtid == 0) P.row_start[NN] = E;
    }
    grid.sync();

    // ---- P4: scatter + GEMM1 (x f32 -> hlin bf16, + scores1) ----
    for (int e = gtid; e < E; e += gsz) {
        int d = P.dst[e];
        int pos = P.row_start[d] + atomicAdd(&P.cursor[d], 1);
        P.sperm[pos] = P.src[e];
    }
    for (int unit = bid; unit < 782; unit += nb) gemm_unit<true>(P, unit, As, Bs);
    grid.sync();

    // ---- P5: m,z for layer 1 ----
    for (int node = gw; node < NN; node += nw) {
        int b = P.row_start[node], e2 = P.row_start[node + 1];
        float sd = P.s1d[node];
        float m = -INFINITY;
        for (int j0 = b; j0 < e2; j0 += 64) {
            int idx = j0 + lane;
            float tv = -INFINITY;
            if (idx < e2) {
                float q = P.s1s[P.sperm[idx]] + sd;
                tv = (q > 0.f) ? q : 0.2f * q;
            }
#pragma unroll
            for (int off = 32; off; off >>= 1) tv = fmaxf(tv, __shfl_xor(tv, off));
            m = fmaxf(m, tv);
        }
        float z = 0.f;
        for (int j0 = b; j0 < e2; j0 += 64) {
            int idx = j0 + lane;
            if (idx < e2) {
                float q = P.s1s[P.sperm[idx]] + sd;
                q = (q > 0.f) ? q : 0.2f * q;
                z += __expf(q - m);
            }
        }
#pragma unroll
        for (int off = 32; off; off >>= 1) z += __shfl_xor(z, off);
        if (lane == 0) {
            P.m1[node] = m;
            P.zi1[node] = 1.f / (z + 1e-16f);
        }
    }
    grid.sync();

    // ---- P6: gather1 -> h (relu(agg + b1)) ----
    for (int node = gw; node < NN; node += nw) {
        int b = P.row_start[node], e2 = P.row_start[node + 1];
        float sd = P.s1d[node], mm = P.m1[node], zi = P.zi1[node];
        float acc[8];
#pragma unroll
        for (int u = 0; u < 8; u++) acc[u] = 0.f;
        for (int j0 = b; j0 < e2; j0 += 64) {
            int idx = j0 + lane;
            bool v = idx < e2;
            int s_l = v ? P.sperm[idx] : 0;
            float p_l = 0.f;
            if (v) {
                float q = P.s1s[s_l] + sd;
                q = (q > 0.f) ? q : 0.2f * q;
                p_l = __expf(q - mm) * zi;
            }
            int cnt = min(64, e2 - j0);
            int iters = (cnt + 1) >> 1;
            for (int i = 0; i < iters; i++) {
                int tt = 2 * i + half;
                int tc = min(tt, cnt - 1);
                float w = __shfl(p_l, tc);
                if (tt >= cnt) w = 0.f;
                int s = __shfl(s_l, tc);
                uint4 d = *((const uint4*)(P.hlin + (size_t)s * 256) + l31);
                fma8(acc, d, w);
            }
        }
#pragma unroll
        for (int u = 0; u < 8; u++) acc[u] += __shfl_xor(acc[u], 32);
        if (half == 0) {
            int c = l31 * 8;
            float4 b0 = *(const float4*)(P.b1 + c);
            float4 b1v = *(const float4*)(P.b1 + c + 4);
            float o0 = fmaxf(acc[0] + b0.x, 0.f), o1 = fmaxf(acc[1] + b0.y, 0.f);
            float o2 = fmaxf(acc[2] + b0.z, 0.f), o3 = fmaxf(acc[3] + b0.w, 0.f);
            float o4 = fmaxf(acc[4] + b1v.x, 0.f), o5 = fmaxf(acc[5] + b1v.y, 0.f);
            float o6 = fmaxf(acc[6] + b1v.z, 0.f), o7 = fmaxf(acc[7] + b1v.w, 0.f);
            uint4 st;
            st.x = ((unsigned)f2bf(o1) << 16) | f2bf(o0);
            st.y = ((unsigned)f2bf(o3) << 16) | f2bf(o2);
            st.z = ((unsigned)f2bf(o5) << 16) | f2bf(o4);
            st.w = ((unsigned)f2bf(o7) << 16) | f2bf(o6);
            *(uint4*)(P.h + (size_t)node * 256 + c) = st;
        }
    }
    grid.sync();

    // ---- P7: GEMM2 (h -> hcat, + mu/ls scores) ----
    for (int unit = bid; unit < 782; unit += nb) gemm_unit<false>(P, unit, As, Bs);
    grid.sync();

    // ---- P8: m,z for both heads ----
    for (int node = gw; node < NN; node += nw) {
        int b = P.row_start[node], e2 = P.row_start[node + 1];
        float sdm = P.smd[node], sdl = P.sld[node];
        float mM = -INFINITY, mL = -INFINITY;
        for (int j0 = b; j0 < e2; j0 += 64) {
            int idx = j0 + lane;
            float tM = -INFINITY, tL = -INFINITY;
            if (idx < e2) {
                int s = P.sperm[idx];
                float qm = P.sms[s] + sdm;
                tM = (qm > 0.f) ? qm : 0.2f * qm;
                float ql = P.slsv[s] + sdl;
                tL = (ql > 0.f) ? ql : 0.2f * ql;
            }
#pragma unroll
            for (int off = 32; off; off >>= 1) {
                tM = fmaxf(tM, __shfl_xor(tM, off));
                tL = fmaxf(tL, __shfl_xor(tL, off));
            }
            mM = fmaxf(mM, tM);
            mL = fmaxf(mL, tL);
        }
        float zM = 0.f, zL = 0.f;
        for (int j0 = b; j0 < e2; j0 += 64) {
            int idx = j0 + lane;
            if (idx < e2) {
                int s = P.sperm[idx];
                float qm = P.sms[s] + sdm;
                qm = (qm > 0.f) ? qm : 0.2f * qm;
                zM += __expf(qm - mM);
                float ql = P.slsv[s] + sdl;
                ql = (ql > 0.f) ? ql : 0.2f * ql;
                zL += __expf(ql - mL);
            }
        }
#pragma unroll
        for (int off = 32; off; off >>= 1) {
            zM += __shfl_xor(zM, off);
            zL += __shfl_xor(zL, off);
        }
        if (lane == 0) {
            P.mmu[node] = mM;  P.zimu[node] = 1.f / (zM + 1e-16f);
            P.mls[node] = mL;  P.zils[node] = 1.f / (zL + 1e-16f);
        }
    }
    grid.sync();

    // ---- P9: dual-head gather -> out ----
    for (int node = gw; node < NN; node += nw) {
        int b = P.row_start[node], e2 = P.row_start[node + 1];
        float sdm = P.smd[node], sdl = P.sld[node];
        float mM = P.mmu[node], ziM = P.zimu[node];
        float mL = P.mls[node], ziL = P.zils[node];
        bool isMu = l31 < 16;
        float acc[8];
#pragma unroll
        for (int u = 0; u < 8; u++) acc[u] = 0.f;
        for (int j0 = b; j0 < e2; j0 += 64) {
            int idx = j0 + lane;
            bool v = idx < e2;
            int s_l = v ? P.sperm[idx] : 0;
            float pM = 0.f, pL = 0.f;
            if (v) {
                float qm = P.sms[s_l] + sdm;
                qm = (qm > 0.f) ? qm : 0.2f * qm;
                pM = __expf(qm - mM) * ziM;
                float ql = P.slsv[s_l] + sdl;
                ql = (ql > 0.f) ? ql : 0.2f * ql;
                pL = __expf(ql - mL) * ziL;
            }
            int cnt = min(64, e2 - j0);
            int iters = (cnt + 1) >> 1;
            for (int i = 0; i < iters; i++) {
                int tt = 2 * i + half;
                int tc = min(tt, cnt - 1);
                float wM = __shfl(pM, tc);
                float wL = __shfl(pL, tc);
                float w = isMu ? wM : wL;
                if (tt >= cnt) w = 0.f;
                int s = __shfl(s_l, tc);
                uint4 d = *((const uint4*)(P.hcat + (size_t)s * 256) + l31);
                fma8(acc, d, w);
            }
        }
#pragma unroll
        for (int u = 0; u < 8; u++) acc[u] += __shfl_xor(acc[u], 32);
        if (half == 0) {
            int c = isMu ? (l31 * 8) : (l31 * 8 - 128);
            const float* bp = isMu ? P.bmu : P.bls;
            float* op = isMu ? P.out_mu : P.out_ls;
            float4 b0 = *(const float4*)(bp + c);
            float4 b1v = *(const float4*)(bp + c + 4);
            float4 v0 = make_float4(acc[0] + b0.x, acc[1] + b0.y, acc[2] + b0.z, acc[3] + b0.w);
            float4 v1 = make_float4(acc[4] + b1v.x, acc[5] + b1v.y, acc[6] + b1v.z, acc[7] + b1v.w);
            *(float4*)(op + (size_t)node * 128 + c) = v0;
            *(float4*)(op + (size_t)node * 128 + c + 4) = v1;
        }
    }
}

// ---------------- launch ----------------

extern "C" void kernel_launch(void* const* d_in, const int* in_sizes, int n_in,
                              void* d_out, int out_size, void* d_ws, size_t ws_size,
                              hipStream_t stream) {
    const int E = in_sizes[1] / 2;
    const int* ei = (const int*)d_in[1];

    GatP P;
    P.x      = (const float*)d_in[0];
    P.src    = ei;
    P.dst    = ei + E;
    P.E      = E;
    P.W1     = (const float*)d_in[2];
    P.a_src1 = (const float*)d_in[3];
    P.a_dst1 = (const float*)d_in[4];
    P.b1     = (const float*)d_in[5];
    P.Wmu    = (const float*)d_in[6];
    P.aSmu   = (const float*)d_in[7];
    P.aDmu   = (const float*)d_in[8];
    P.bmu    = (const float*)d_in[9];
    P.Wls    = (const float*)d_in[10];
    P.aSls   = (const float*)d_in[11];
    P.aDls   = (const float*)d_in[12];
    P.bls    = (const float*)d_in[13];

    const size_t NM = (size_t)NN * 256;
    char* w = (char*)d_ws;
    P.W1t  = (unsigned short*)w;  w += 65536 * 2;
    P.Wct  = (unsigned short*)w;  w += 65536 * 2;
    P.hlin = (unsigned short*)w;  w += NM * 2;
    P.h    = (unsigned short*)w;  w += NM * 2;
    P.hcat = (unsigned short*)w;  w += NM * 2;
    P.s1s  = (float*)w;  w += NN * 4;    // 6 contiguous score arrays (zeroed as one)
    P.s1d  = (float*)w;  w += NN * 4;
    P.sms  = (float*)w;  w += NN * 4;
    P.smd  = (float*)w;  w += NN * 4;
    P.slsv = (float*)w;  w += NN * 4;
    P.sld  = (float*)w;  w += NN * 4;
    P.m1   = (float*)w;  w += NN * 4;
    P.zi1  = (float*)w;  w += NN * 4;
    P.mmu  = (float*)w;  w += NN * 4;
    P.zimu = (float*)w;  w += NN * 4;
    P.mls  = (float*)w;  w += NN * 4;
    P.zils = (float*)w;  w += NN * 4;
    P.cnt    = (int*)w;  w += NN * 4;    // cnt + cursor contiguous (zeroed as one)
    P.cursor = (int*)w;  w += NN * 4;
    P.bsum   = (int*)w;  w += 256 * 4;
    P.row_start = (int*)w;  w += (NN + 1) * 4;
    P.sperm  = (int*)w;  w += (size_t)E * 4;
    P.out_mu = (float*)d_out;
    P.out_ls = P.out_mu + (size_t)NN * 128;

    int occ = 0;
    hipOccupancyMaxActiveBlocksPerMultiprocessor(&occ, gat_mega, 256, 0);
    if (occ < 1) occ = 1;
    int blocks = occ * 256;          // 256 CUs on MI355X
    if (blocks > 1024) blocks = 1024;

    void* args[] = { &P };
    hipLaunchCooperativeKernel((void*)gat_mega, dim3(blocks), dim3(256), args, 0, stream);
}

// Round 6
// 440.875 us; speedup vs baseline: 2.5393x; 2.5393x over previous
//
#include <hip/hip_runtime.h>
#include <math.h>

// ---------------------------------------------------------------------------
// VariationalGATEncoder round 6: 7 graph nodes (was 19).
// R5 post-mortem: mega-kernel halved occupancy (uniform 21.5KB LDS + 80 VGPR
// across all phases) and paid 9 grid barriers -> 2.6x regression. Reverted to
// conventional kernels; dispatch count attacked by fusion instead:
//   N0 memset(scores|cnt|cursor)   N1 prep(transposes+count)
//   N2 single-block scan           N3 scatter + GEMM1(+fused scores)
//   N4 gather1 (inline m,z)        N5 GEMM2(+fused scores)
//   N6 gather_cat (inline m,z)
// ---------------------------------------------------------------------------

#define NN 50000

typedef __attribute__((ext_vector_type(8))) short bf16x8;
typedef __attribute__((ext_vector_type(4))) float f32x4;

__device__ __forceinline__ float bf2f(unsigned short u) {
    return __uint_as_float(((unsigned int)u) << 16);
}
__device__ __forceinline__ unsigned short f2bf(float f) {
    unsigned int i = __float_as_uint(f);
    unsigned int r = i + 0x7fffu + ((i >> 16) & 1u);   // RNE
    return (unsigned short)(r >> 16);
}
__device__ __forceinline__ void cvt2(unsigned int d, float& lo, float& hi) {
    lo = __uint_as_float(d << 16);
    hi = __uint_as_float(d & 0xffff0000u);
}
__device__ __forceinline__ void fma8(float* acc, uint4 d, float w) {
    float f0, f1, f2, f3, f4, f5, f6, f7;
    cvt2(d.x, f0, f1); cvt2(d.y, f2, f3); cvt2(d.z, f4, f5); cvt2(d.w, f6, f7);
    acc[0] += w * f0; acc[1] += w * f1; acc[2] += w * f2; acc[3] += w * f3;
    acc[4] += w * f4; acc[5] += w * f5; acc[6] += w * f6; acc[7] += w * f7;
}

struct GatP {
    const float* x;
    const int* src;
    const int* dst;
    int E;
    const float *W1, *a_src1, *a_dst1, *b1;
    const float *Wmu, *aSmu, *aDmu, *bmu;
    const float *Wls, *aSls, *aDls, *bls;
    unsigned short *W1t, *Wct, *hlin, *h, *hcat;
    float *s1s, *s1d, *sms, *smd, *slsv, *sld;   // contiguous w/ cnt,cursor for 1 memset
    int *cnt, *cursor, *row_start, *sperm;
    float *out_mu, *out_ls;
};

// ---- 128x128x256 MFMA GEMM tile (unit = mtile*2 + nhalf) + fused scores ----
template <bool XF32>
__device__ __forceinline__ void gemm_unit(const GatP& P, int unit,
                                          unsigned short* As, unsigned short* Bs) {
    const int t = threadIdx.x;
    int lane = t & 63, w = t >> 6;
    int wm = w & 1, wn = w >> 1;
    int l15 = lane & 15, quad = lane >> 4;
    int mbase = (unit >> 1) * 128, nbase = (unit & 1) * 128;
    const unsigned short* Bt = XF32 ? P.W1t : P.Wct;
    unsigned short* C_ = XF32 ? P.hlin : P.hcat;

    f32x4 acc[4][4];
    const f32x4 zero = {0.f, 0.f, 0.f, 0.f};
#pragma unroll
    for (int mt = 0; mt < 4; mt++)
#pragma unroll
        for (int nt = 0; nt < 4; nt++) acc[mt][nt] = zero;

    for (int k0 = 0; k0 < 256; k0 += 32) {
#pragma unroll
        for (int i = t; i < 512; i += 256) {
            int row = i >> 2, seg = i & 3;
            int gr = mbase + row;
            if constexpr (XF32) {
                float4 a0 = make_float4(0.f, 0.f, 0.f, 0.f), a1 = a0;
                if (gr < NN) {
                    const float* ap = P.x + (size_t)gr * 256 + k0 + seg * 8;
                    a0 = *(const float4*)ap;
                    a1 = *(const float4*)(ap + 4);
                }
                ushort4 lo, hi;
                lo.x = f2bf(a0.x); lo.y = f2bf(a0.y); lo.z = f2bf(a0.z); lo.w = f2bf(a0.w);
                hi.x = f2bf(a1.x); hi.y = f2bf(a1.y); hi.z = f2bf(a1.z); hi.w = f2bf(a1.w);
                *(ushort4*)(&As[row * 40 + seg * 8]) = lo;
                *(ushort4*)(&As[row * 40 + seg * 8 + 4]) = hi;
            } else {
                float4 va = make_float4(0.f, 0.f, 0.f, 0.f);
                if (gr < NN) va = *(const float4*)(P.h + (size_t)gr * 256 + k0 + seg * 8);
                *(float4*)(&As[row * 40 + seg * 8]) = va;
            }
            float4 vb = *(const float4*)(Bt + (size_t)(nbase + row) * 256 + k0 + seg * 8);
            *(float4*)(&Bs[row * 40 + seg * 8]) = vb;
        }
        __syncthreads();
        bf16x8 af[4], bfr[4];
#pragma unroll
        for (int mt = 0; mt < 4; mt++)
            af[mt] = *(const bf16x8*)(&As[(wm * 64 + mt * 16 + l15) * 40 + quad * 8]);
#pragma unroll
        for (int nt = 0; nt < 4; nt++)
            bfr[nt] = *(const bf16x8*)(&Bs[(wn * 64 + nt * 16 + l15) * 40 + quad * 8]);
#pragma unroll
        for (int mt = 0; mt < 4; mt++)
#pragma unroll
            for (int nt = 0; nt < 4; nt++)
                acc[mt][nt] = __builtin_amdgcn_mfma_f32_16x16x32_bf16(af[mt], bfr[nt], acc[mt][nt], 0, 0, 0);
        __syncthreads();
    }

    // epilogue: C store + fused score partials (atomicAdd into zeroed arrays)
    const float *aS, *aD;
    float *sS, *sD;
    int aoff;
    if constexpr (XF32) {
        aS = P.a_src1; aD = P.a_dst1; sS = P.s1s; sD = P.s1d; aoff = nbase;
    } else {
        int nh = unit & 1;
        aS = nh ? P.aSls : P.aSmu;  aD = nh ? P.aDls : P.aDmu;
        sS = nh ? P.slsv : P.sms;   sD = nh ? P.sld  : P.smd;
        aoff = 0;
    }
    float as_[4], ad_[4];
#pragma unroll
    for (int nt = 0; nt < 4; nt++) {
        int ncol = aoff + wn * 64 + nt * 16 + l15;
        as_[nt] = aS[ncol];
        ad_[nt] = aD[ncol];
    }
#pragma unroll
    for (int mt = 0; mt < 4; mt++) {
#pragma unroll
        for (int r = 0; r < 4; r++) {
            int m_ = mbase + wm * 64 + mt * 16 + quad * 4 + r;
            bool ok = m_ < NN;
            float ps = 0.f, pd = 0.f;
#pragma unroll
            for (int nt = 0; nt < 4; nt++) {
                float val = acc[mt][nt][r];
                ps += val * as_[nt];
                pd += val * ad_[nt];
                if (ok) C_[(size_t)m_ * 256 + nbase + wn * 64 + nt * 16 + l15] = f2bf(val);
            }
#pragma unroll
            for (int off = 1; off < 16; off <<= 1) {
                ps += __shfl_xor(ps, off);
                pd += __shfl_xor(pd, off);
            }
            if (ok && l15 == 0) {
                atomicAdd(&sS[m_], ps);
                atomicAdd(&sD[m_], pd);
            }
        }
    }
}

// ---- N1: weight transposes + edge count (one grid-stride space) ----
__global__ __launch_bounds__(256) void prep_kernel(GatP P) {
    int gtid = blockIdx.x * 256 + threadIdx.x, gsz = gridDim.x * 256;
    int total = 131072 + P.E;
    for (int i = gtid; i < total; i += gsz) {
        if (i < 65536) {
            int n = i >> 8, k = i & 255;
            P.W1t[(size_t)n * 256 + k] = f2bf(P.W1[(size_t)k * 256 + n]);
        } else if (i < 131072) {
            int j = i - 65536;
            int n = j >> 8, k = j & 255;
            float v = (n < 128) ? P.Wmu[(size_t)k * 128 + n] : P.Wls[(size_t)k * 128 + (n - 128)];
            P.Wct[(size_t)n * 256 + k] = f2bf(v);
        } else {
            atomicAdd(&P.cnt[P.dst[i - 131072]], 1);
        }
    }
}

// ---- N2: single-block exclusive scan (1024 threads x 49-run each) ----
__global__ __launch_bounds__(1024) void scan_block(const int* __restrict__ cnt,
                                                   int* __restrict__ row_start, int E) {
    __shared__ int part[1024];
    int t = threadIdx.x;
    const int RUN = (NN + 1023) / 1024;   // 49
    int b = t * RUN, e = min(b + RUN, NN);
    int s = 0;
    for (int i = b; i < e; i++) s += cnt[i];
    part[t] = s;
    __syncthreads();
    for (int off = 1; off < 1024; off <<= 1) {
        int add = (t >= off) ? part[t - off] : 0;
        __syncthreads();
        part[t] += add;
        __syncthreads();
    }
    int excl = part[t] - s;
    for (int i = b; i < e; i++) {
        int c = cnt[i];
        row_start[i] = excl;
        excl += c;
    }
    if (t == 1023) row_start[NN] = E;
}

// ---- N3: scatter (blocks >= 782) + GEMM1 with fused scores (blocks < 782) ----
__global__ __launch_bounds__(256) void scatter_gemm1(GatP P) {
    __shared__ __align__(16) unsigned short As[128 * 40];
    __shared__ __align__(16) unsigned short Bs[128 * 40];
    if (blockIdx.x < 782) {
        gemm_unit<true>(P, blockIdx.x, As, Bs);
    } else {
        int sb = blockIdx.x - 782, nsb = gridDim.x - 782;
        for (int e = sb * 256 + threadIdx.x; e < P.E; e += nsb * 256) {
            int d = P.dst[e];
            int pos = P.row_start[d] + atomicAdd(&P.cursor[d], 1);
            P.sperm[pos] = P.src[e];
        }
    }
}

// ---- N5: GEMM2 with fused mu/ls scores ----
__global__ __launch_bounds__(256) void gemm2_kernel(GatP P) {
    __shared__ __align__(16) unsigned short As[128 * 40];
    __shared__ __align__(16) unsigned short Bs[128 * 40];
    gemm_unit<false>(P, blockIdx.x, As, Bs);
}

// ---- N4: gather layer 1, inline m/z (fast path deg<=64) ----
__global__ __launch_bounds__(256) void gather1(GatP P) {
    int wid = threadIdx.x >> 6, lane = threadIdx.x & 63;
    int node = blockIdx.x * 4 + wid;
    if (node >= NN) return;
    int b = P.row_start[node], e2 = P.row_start[node + 1];
    int deg = e2 - b;
    float sd = P.s1d[node];
    int half = lane >> 5, l31 = lane & 31;
    float acc[8];
#pragma unroll
    for (int u = 0; u < 8; u++) acc[u] = 0.f;

    if (deg <= 64) {
        int idx = b + lane;
        bool v = lane < deg;
        int s_l = v ? P.sperm[idx] : 0;
        float e_l = -INFINITY;
        if (v) {
            float q = P.s1s[s_l] + sd;
            e_l = (q > 0.f) ? q : 0.2f * q;
        }
        float m = e_l;
#pragma unroll
        for (int off = 32; off; off >>= 1) m = fmaxf(m, __shfl_xor(m, off));
        float p_l = v ? __expf(e_l - m) : 0.f;
        float z = p_l;
#pragma unroll
        for (int off = 32; off; off >>= 1) z += __shfl_xor(z, off);
        p_l *= 1.f / (z + 1e-16f);
        int iters = (deg + 1) >> 1;
        for (int i = 0; i < iters; i++) {
            int tt = 2 * i + half;
            int tc = min(tt, deg - 1);
            float w = __shfl(p_l, tc);
            if (tt >= deg) w = 0.f;
            int s = __shfl(s_l, tc);
            uint4 d = *((const uint4*)(P.hlin + (size_t)s * 256) + l31);
            fma8(acc, d, w);
        }
    } else {
        float m = -INFINITY;
        for (int j0 = b; j0 < e2; j0 += 64) {
            int idx = j0 + lane;
            float tv = -INFINITY;
            if (idx < e2) {
                float q = P.s1s[P.sperm[idx]] + sd;
                tv = (q > 0.f) ? q : 0.2f * q;
            }
#pragma unroll
            for (int off = 32; off; off >>= 1) tv = fmaxf(tv, __shfl_xor(tv, off));
            m = fmaxf(m, tv);
        }
        float z = 0.f;
        for (int j0 = b; j0 < e2; j0 += 64) {
            int idx = j0 + lane;
            if (idx < e2) {
                float q = P.s1s[P.sperm[idx]] + sd;
                q = (q > 0.f) ? q : 0.2f * q;
                z += __expf(q - m);
            }
        }
#pragma unroll
        for (int off = 32; off; off >>= 1) z += __shfl_xor(z, off);
        float zi = 1.f / (z + 1e-16f);
        for (int j0 = b; j0 < e2; j0 += 64) {
            int idx = j0 + lane;
            bool v = idx < e2;
            int s_l = v ? P.sperm[idx] : 0;
            float p_l = 0.f;
            if (v) {
                float q = P.s1s[s_l] + sd;
                q = (q > 0.f) ? q : 0.2f * q;
                p_l = __expf(q - m) * zi;
            }
            int cnt = min(64, e2 - j0);
            int iters = (cnt + 1) >> 1;
            for (int i = 0; i < iters; i++) {
                int tt = 2 * i + half;
                int tc = min(tt, cnt - 1);
                float w = __shfl(p_l, tc);
                if (tt >= cnt) w = 0.f;
                int s = __shfl(s_l, tc);
                uint4 d = *((const uint4*)(P.hlin + (size_t)s * 256) + l31);
                fma8(acc, d, w);
            }
        }
    }
#pragma unroll
    for (int u = 0; u < 8; u++) acc[u] += __shfl_xor(acc[u], 32);
    if (half == 0) {
        int c = l31 * 8;
        float4 b0 = *(const float4*)(P.b1 + c);
        float4 b1v = *(const float4*)(P.b1 + c + 4);
        float o0 = fmaxf(acc[0] + b0.x, 0.f), o1 = fmaxf(acc[1] + b0.y, 0.f);
        float o2 = fmaxf(acc[2] + b0.z, 0.f), o3 = fmaxf(acc[3] + b0.w, 0.f);
        float o4 = fmaxf(acc[4] + b1v.x, 0.f), o5 = fmaxf(acc[5] + b1v.y, 0.f);
        float o6 = fmaxf(acc[6] + b1v.z, 0.f), o7 = fmaxf(acc[7] + b1v.w, 0.f);
        uint4 st;
        st.x = ((unsigned)f2bf(o1) << 16) | f2bf(o0);
        st.y = ((unsigned)f2bf(o3) << 16) | f2bf(o2);
        st.z = ((unsigned)f2bf(o5) << 16) | f2bf(o4);
        st.w = ((unsigned)f2bf(o7) << 16) | f2bf(o6);
        *(uint4*)(P.h + (size_t)node * 256 + c) = st;
    }
}

// ---- N6: dual-head gather, inline m/z ----
__global__ __launch_bounds__(256) void gather_cat(GatP P) {
    int wid = threadIdx.x >> 6, lane = threadIdx.x & 63;
    int node = blockIdx.x * 4 + wid;
    if (node >= NN) return;
    int b = P.row_start[node], e2 = P.row_start[node + 1];
    int deg = e2 - b;
    float sdm = P.smd[node], sdl = P.sld[node];
    int half = lane >> 5, l31 = lane & 31;
    bool isMu = l31 < 16;
    float acc[8];
#pragma unroll
    for (int u = 0; u < 8; u++) acc[u] = 0.f;

    if (deg <= 64) {
        int idx = b + lane;
        bool v = lane < deg;
        int s_l = v ? P.sperm[idx] : 0;
        float eM = -INFINITY, eL = -INFINITY;
        if (v) {
            float qm = P.sms[s_l] + sdm;
            eM = (qm > 0.f) ? qm : 0.2f * qm;
            float ql = P.slsv[s_l] + sdl;
            eL = (ql > 0.f) ? ql : 0.2f * ql;
        }
        float mM = eM, mL = eL;
#pragma unroll
        for (int off = 32; off; off >>= 1) {
            mM = fmaxf(mM, __shfl_xor(mM, off));
            mL = fmaxf(mL, __shfl_xor(mL, off));
        }
        float pM = v ? __expf(eM - mM) : 0.f;
        float pL = v ? __expf(eL - mL) : 0.f;
        float zM = pM, zL = pL;
#pragma unroll
        for (int off = 32; off; off >>= 1) {
            zM += __shfl_xor(zM, off);
            zL += __shfl_xor(zL, off);
        }
        pM *= 1.f / (zM + 1e-16f);
        pL *= 1.f / (zL + 1e-16f);
        int iters = (deg + 1) >> 1;
        for (int i = 0; i < iters; i++) {
            int tt = 2 * i + half;
            int tc = min(tt, deg - 1);
            float wM = __shfl(pM, tc);
            float wL = __shfl(pL, tc);
            float w = isMu ? wM : wL;
            if (tt >= deg) w = 0.f;
            int s = __shfl(s_l, tc);
            uint4 d = *((const uint4*)(P.hcat + (size_t)s * 256) + l31);
            fma8(acc, d, w);
        }
    } else {
        float mM = -INFINITY, mL = -INFINITY;
        for (int j0 = b; j0 < e2; j0 += 64) {
            int idx = j0 + lane;
            float tM = -INFINITY, tL = -INFINITY;
            if (idx < e2) {
                int s = P.sperm[idx];
                float qm = P.sms[s] + sdm;
                tM = (qm > 0.f) ? qm : 0.2f * qm;
                float ql = P.slsv[s] + sdl;
                tL = (ql > 0.f) ? ql : 0.2f * ql;
            }
#pragma unroll
            for (int off = 32; off; off >>= 1) {
                tM = fmaxf(tM, __shfl_xor(tM, off));
                tL = fmaxf(tL, __shfl_xor(tL, off));
            }
            mM = fmaxf(mM, tM);
            mL = fmaxf(mL, tL);
        }
        float zM = 0.f, zL = 0.f;
        for (int j0 = b; j0 < e2; j0 += 64) {
            int idx = j0 + lane;
            if (idx < e2) {
                int s = P.sperm[idx];
                float qm = P.sms[s] + sdm;
                qm = (qm > 0.f) ? qm : 0.2f * qm;
                zM += __expf(qm - mM);
                float ql = P.slsv[s] + sdl;
                ql = (ql > 0.f) ? ql : 0.2f * ql;
                zL += __expf(ql - mL);
            }
        }
#pragma unroll
        for (int off = 32; off; off >>= 1) {
            zM += __shfl_xor(zM, off);
            zL += __shfl_xor(zL, off);
        }
        float ziM = 1.f / (zM + 1e-16f);
        float ziL = 1.f / (zL + 1e-16f);
        for (int j0 = b; j0 < e2; j0 += 64) {
            int idx = j0 + lane;
            bool v = idx < e2;
            int s_l = v ? P.sperm[idx] : 0;
            float pM = 0.f, pL = 0.f;
            if (v) {
                float qm = P.sms[s_l] + sdm;
                qm = (qm > 0.f) ? qm : 0.2f * qm;
                pM = __expf(qm - mM) * ziM;
                float ql = P.slsv[s_l] + sdl;
                ql = (ql > 0.f) ? ql : 0.2f * ql;
                pL = __expf(ql - mL) * ziL;
            }
            int cnt = min(64, e2 - j0);
            int iters = (cnt + 1) >> 1;
            for (int i = 0; i < iters; i++) {
                int tt = 2 * i + half;
                int tc = min(tt, cnt - 1);
                float wM = __shfl(pM, tc);
                float wL = __shfl(pL, tc);
                float w = isMu ? wM : wL;
                if (tt >= cnt) w = 0.f;
                int s = __shfl(s_l, tc);
                uint4 d = *((const uint4*)(P.hcat + (size_t)s * 256) + l31);
                fma8(acc, d, w);
            }
        }
    }
#pragma unroll
    for (int u = 0; u < 8; u++) acc[u] += __shfl_xor(acc[u], 32);
    if (half == 0) {
        int c = isMu ? (l31 * 8) : (l31 * 8 - 128);
        const float* bp = isMu ? P.bmu : P.bls;
        float* op = isMu ? P.out_mu : P.out_ls;
        float4 b0 = *(const float4*)(bp + c);
        float4 b1v = *(const float4*)(bp + c + 4);
        float4 v0 = make_float4(acc[0] + b0.x, acc[1] + b0.y, acc[2] + b0.z, acc[3] + b0.w);
        float4 v1 = make_float4(acc[4] + b1v.x, acc[5] + b1v.y, acc[6] + b1v.z, acc[7] + b1v.w);
        *(float4*)(op + (size_t)node * 128 + c) = v0;
        *(float4*)(op + (size_t)node * 128 + c + 4) = v1;
    }
}

// ---------------- launch ----------------

extern "C" void kernel_launch(void* const* d_in, const int* in_sizes, int n_in,
                              void* d_out, int out_size, void* d_ws, size_t ws_size,
                              hipStream_t stream) {
    const int E = in_sizes[1] / 2;
    const int* ei = (const int*)d_in[1];

    GatP P;
    P.x      = (const float*)d_in[0];
    P.src    = ei;
    P.dst    = ei + E;
    P.E      = E;
    P.W1     = (const float*)d_in[2];
    P.a_src1 = (const float*)d_in[3];
    P.a_dst1 = (const float*)d_in[4];
    P.b1     = (const float*)d_in[5];
    P.Wmu    = (const float*)d_in[6];
    P.aSmu   = (const float*)d_in[7];
    P.aDmu   = (const float*)d_in[8];
    P.bmu    = (const float*)d_in[9];
    P.Wls    = (const float*)d_in[10];
    P.aSls   = (const float*)d_in[11];
    P.aDls   = (const float*)d_in[12];
    P.bls    = (const float*)d_in[13];

    const size_t NM = (size_t)NN * 256;
    char* w = (char*)d_ws;
    P.W1t  = (unsigned short*)w;  w += 65536 * 2;
    P.Wct  = (unsigned short*)w;  w += 65536 * 2;
    P.hlin = (unsigned short*)w;  w += NM * 2;
    P.h    = (unsigned short*)w;  w += NM * 2;
    P.hcat = (unsigned short*)w;  w += NM * 2;
    // 6 score arrays + cnt + cursor contiguous -> single memset
    P.s1s  = (float*)w;  w += NN * 4;
    P.s1d  = (float*)w;  w += NN * 4;
    P.sms  = (float*)w;  w += NN * 4;
    P.smd  = (float*)w;  w += NN * 4;
    P.slsv = (float*)w;  w += NN * 4;
    P.sld  = (float*)w;  w += NN * 4;
    P.cnt    = (int*)w;  w += NN * 4;
    P.cursor = (int*)w;  w += NN * 4;
    P.row_start = (int*)w;  w += (NN + 1) * 4;
    P.sperm  = (int*)w;  w += (size_t)E * 4;
    P.out_mu = (float*)d_out;
    P.out_ls = P.out_mu + (size_t)NN * 128;

    const int ngrid4 = (NN + 3) / 4;   // 12500

    // N0: zero scores + cnt + cursor (one contiguous range)
    hipMemsetAsync(P.s1s, 0, (size_t)8 * NN * 4, stream);
    // N1: transposes + count
    prep_kernel<<<2048, 256, 0, stream>>>(P);
    // N2: scan
    scan_block<<<1, 1024, 0, stream>>>(P.cnt, P.row_start, E);
    // N3: scatter + GEMM1(+scores)
    scatter_gemm1<<<782 + 512, 256, 0, stream>>>(P);
    // N4: gather layer 1 -> h
    gather1<<<ngrid4, 256, 0, stream>>>(P);
    // N5: GEMM2(+scores)
    gemm2_kernel<<<782, 256, 0, stream>>>(P);
    // N6: dual-head gather -> out
    gather_cat<<<ngrid4, 256, 0, stream>>>(P);
}